// Round 1
// baseline (1868.169 us; speedup 1.0000x reference)
//
#include <hip/hip_runtime.h>
#include <hip/hip_bf16.h>
#include <stdint.h>

#define B_ 64
#define S_ 50
#define NSK 512
#define DK 128

// ws layout (float offsets)
#define LEARN_OFF 0u
#define PREL_OFF  409600u
#define PREG_OFF  819200u
#define PREF_OFF  1228800u
#define PREP_OFF  1638400u
#define HM_OFF    2048000u
// total floats = 2048000 + 64*512*128 = 6242304  (~23.8 MB)

typedef float  f32x4  __attribute__((ext_vector_type(4)));
typedef short  s16x8  __attribute__((ext_vector_type(8)));
typedef __bf16 bf16x8 __attribute__((ext_vector_type(8)));

static __device__ __forceinline__ bf16x8 as_bf(s16x8 v){ return __builtin_bit_cast(bf16x8, v); }

static __device__ __forceinline__ unsigned short f2bf(float x){
  unsigned int u = __builtin_bit_cast(unsigned int, x);
  u += 0x7FFFu + ((u>>16)&1u);
  return (unsigned short)(u>>16);
}
static __device__ __forceinline__ float sigm(float x){ return 1.f/(1.f + __expf(-x)); }

// -------------------- K1: learning[b,t,j] --------------------
__global__ __launch_bounds__(512) void k_learning(
    const float* __restrict__ E_emb, const float* __restrict__ AT_emb,
    const float* __restrict__ W_le, const float* __restrict__ b_le,
    const float* __restrict__ answer, const int* __restrict__ ex_id,
    const int* __restrict__ at_id, float* __restrict__ learn_ws)
{
  int b = blockIdx.x >> 2, jg = blockIdx.x & 3;
  int tid = threadIdx.x; int w = tid >> 6; int l = tid & 63;
  __shared__ float exv[S_][128];
  __shared__ float atv[S_][128];
  __shared__ float ansv[S_];
  for (int idx = tid; idx < S_*128; idx += 512) {
    int t = idx >> 7, d = idx & 127;
    exv[t][d] = E_emb[(size_t)ex_id[b*S_+t]*128 + d];
    atv[t][d] = AT_emb[(size_t)at_id[b*S_+t]*128 + d];
  }
  if (tid < S_) ansv[tid] = answer[b*S_+tid];
  __syncthreads();
  for (int jj = 0; jj < 4; ++jj) {
    int jrow = jg*32 + w + 8*jj;
    float wv[5];
    int base = l*5;
    #pragma unroll
    for (int q = 0; q < 5; ++q) { int i = base+q; wv[q] = (i < 306) ? W_le[jrow*306 + i] : 0.f; }
    float bj = b_le[jrow];
    for (int t = 0; t < S_; ++t) {
      float pacc = 0.f;
      #pragma unroll
      for (int q = 0; q < 5; ++q) {
        int i = base+q;
        float v = 0.f;
        if (i < 128) v = exv[t][i];
        else if (i < 256) v = atv[t][i-128];
        else if (i < 306) v = ansv[t];
        pacc += wv[q]*v;
      }
      #pragma unroll
      for (int m = 1; m < 64; m <<= 1) pacc += __shfl_xor(pacc, m, 64);
      if (l == 0) learn_ws[(size_t)(b*S_+t)*DK + jrow] = pacc + bj;
    }
  }
}

// -------------------- K2: pre_l/pre_g/pre_f/pre_p --------------------
__global__ __launch_bounds__(512) void k_pre(
    const float* __restrict__ IT_emb, const float* __restrict__ E_emb,
    const float* __restrict__ W_l, const float* __restrict__ b_l,
    const float* __restrict__ W_g, const float* __restrict__ b_g,
    const float* __restrict__ W_f, const float* __restrict__ b_f,
    const float* __restrict__ W_p, const float* __restrict__ b_p,
    const int* __restrict__ ex_id, const int* __restrict__ it_sec,
    const float* __restrict__ learn_ws, float* __restrict__ ws)
{
  int b = blockIdx.x >> 2, jg = blockIdx.x & 3;
  int tid = threadIdx.x; int w = tid >> 6; int l = tid & 63;
  __shared__ float itv[S_][128];
  __shared__ float llds[S_][128];
  __shared__ float exv[S_][128];
  for (int idx = tid; idx < S_*128; idx += 512) {
    int t = idx >> 7, d = idx & 127;
    int itm = it_sec[b*S_+t] / 60; if (itm > 1439) itm = 1439; if (itm < 0) itm = 0;
    itv[t][d]  = IT_emb[(size_t)itm*128 + d];
    llds[t][d] = learn_ws[(size_t)(b*S_+t)*DK + d];
    exv[t][d]  = E_emb[(size_t)ex_id[b*S_+t]*128 + d];
  }
  __syncthreads();
  for (int jj = 0; jj < 4; ++jj) {
    int jrow = jg*32 + w + 8*jj;
    float wl[6], wg[6];
    int base6 = l*6;
    #pragma unroll
    for (int q = 0; q < 6; ++q) { wl[q] = W_l[jrow*512 + base6+q]; wg[q] = W_g[jrow*512 + base6+q]; }
    float wfv[2], wpv[2];
    int base2 = l*2;
    #pragma unroll
    for (int q = 0; q < 2; ++q) { wfv[q] = W_f[jrow*384 + 256 + base2+q]; wpv[q] = W_p[jrow*256 + base2+q]; }
    float bl = b_l[jrow], bg = b_g[jrow], bfs = b_f[jrow], bp = b_p[jrow];
    for (int t = 0; t < S_; ++t) {
      float pl = 0.f, pg = 0.f, pf = 0.f, pp = 0.f;
      #pragma unroll
      for (int q = 0; q < 6; ++q) {
        int i = base6+q;
        float v;
        if (i < 128) v = (t > 0) ? llds[t-1][i] : 0.f;
        else if (i < 256) v = itv[t][i-128];
        else v = llds[t][i-256];
        pl += wl[q]*v; pg += wg[q]*v;
      }
      #pragma unroll
      for (int q = 0; q < 2; ++q) {
        pf += wfv[q]*itv[t][base2+q];
        pp += wpv[q]*exv[t][base2+q];
      }
      #pragma unroll
      for (int m = 1; m < 64; m <<= 1) {
        pl += __shfl_xor(pl, m, 64);
        pg += __shfl_xor(pg, m, 64);
        pf += __shfl_xor(pf, m, 64);
        pp += __shfl_xor(pp, m, 64);
      }
      if (l == 0) {
        size_t o = (size_t)(b*S_+t)*DK + jrow;
        ws[PREL_OFF + o] = pl + bl;
        ws[PREG_OFF + o] = pg + bg;
        ws[PREF_OFF + o] = pf + bfs;
        ws[PREP_OFF + o] = pp + bp;
      }
    }
  }
}

// -------------------- K3: sequential scan --------------------
__global__ __launch_bounds__(512) void k_scan(
    const float* __restrict__ q_matrix, const float* __restrict__ h0,
    const float* __restrict__ W_l, const float* __restrict__ W_g,
    const float* __restrict__ W_f, const float* __restrict__ W_p,
    const int* __restrict__ ex_id, const float* __restrict__ ws,
    float* __restrict__ hm_ws, float* __restrict__ pred)
{
  int b = blockIdx.x;
  int tid = threadIdx.x;
  int w  = tid >> 6;          // wave 0..7
  int l  = tid & 63;          // lane
  int wj = w & 1;             // j-half (output-dim half)
  int wn = w >> 1;            // skill quarter
  int lr  = l & 15;
  int lg4 = l >> 4;

  __shared__ __align__(16) unsigned short h_sh[NSK*DK];  // 128KB bf16, swizzled
  __shared__ float qbuf[2][NSK];
  __shared__ float LG_l[DK];
  __shared__ float cf_l[DK];
  __shared__ float htp_l[4][DK];
  __shared__ float ysum_l[8];

  float* hm = hm_ws + (size_t)b*NSK*DK;

  // ---- W_f1 fragments (A operand), held in VGPRs for the whole scan ----
  s16x8 wfr[4][4];
  #pragma unroll
  for (int jt = 0; jt < 4; ++jt) {
    #pragma unroll
    for (int k = 0; k < 4; ++k) {
      int jrow = wj*64 + jt*16 + lr;
      int dbase = k*32 + lg4*8;
      const float* src = W_f + jrow*384 + dbase;
      s16x8 f;
      #pragma unroll
      for (int q = 0; q < 8; ++q) f[q] = (short)f2bf(src[q]);
      wfr[jt][k] = f;
    }
  }

  // ---- init: hm = h0 (per block copy); stage q_0; pred[b][0]=0 ----
  {
    int s = tid; // skill row
    for (int c = 0; c < DK; c += 4) {
      f32x4 a = *(const f32x4*)(h0 + (size_t)s*DK + c);
      *(f32x4*)(hm + (size_t)s*DK + c) = a;
    }
    qbuf[0][tid] = q_matrix[(size_t)ex_id[b*S_]*NSK + tid];
    if (tid == 0) pred[b*S_] = 0.f;
  }
  __syncthreads();
  // ---- h_tilde0 partials ----
  {
    int d = tid & 127, g = tid >> 7;
    float acc = 0.f;
    for (int n = g*128; n < g*128 + 128; ++n) acc += qbuf[0][n] * h0[(size_t)n*DK + d];
    htp_l[g][d] = acc;
  }
  __syncthreads();

  const float* pre_l = ws + PREL_OFF + (size_t)b*S_*DK;
  const float* pre_g = ws + PREG_OFF + (size_t)b*S_*DK;
  const float* pre_f = ws + PREF_OFF + (size_t)b*S_*DK;
  const float* pre_p = ws + PREP_OFF + (size_t)b*S_*DK;

  int jrow = tid >> 2, p = tid & 3;

  for (int tau = 0; tau < S_; ++tau) {
    // ================= G1: LG + y(tau-1) + q staging =================
    {
      float accL = 0.f, accG = 0.f, accY = 0.f;
      const float* wl4 = W_l + jrow*512 + 384;
      const float* wg4 = W_g + jrow*512 + 384;
      const float* wp2 = W_p + jrow*256 + 128;
      #pragma unroll
      for (int c0 = 0; c0 < 32; c0 += 4) {
        int c = p*32 + c0;
        f32x4 t0 = *(const f32x4*)&htp_l[0][c];
        f32x4 t1 = *(const f32x4*)&htp_l[1][c];
        f32x4 t2 = *(const f32x4*)&htp_l[2][c];
        f32x4 t3 = *(const f32x4*)&htp_l[3][c];
        f32x4 hv = t0 + t1 + t2 + t3;
        f32x4 a  = *(const f32x4*)(wl4 + c);
        f32x4 g4 = *(const f32x4*)(wg4 + c);
        f32x4 y4 = *(const f32x4*)(wp2 + c);
        accL += a[0]*hv[0] + a[1]*hv[1] + a[2]*hv[2] + a[3]*hv[3];
        accG += g4[0]*hv[0] + g4[1]*hv[1] + g4[2]*hv[2] + g4[3]*hv[3];
        accY += y4[0]*hv[0] + y4[1]*hv[1] + y4[2]*hv[2] + y4[3]*hv[3];
      }
      accL += __shfl_xor(accL, 1, 64); accL += __shfl_xor(accL, 2, 64);
      accG += __shfl_xor(accG, 1, 64); accG += __shfl_xor(accG, 2, 64);
      accY += __shfl_xor(accY, 1, 64); accY += __shfl_xor(accY, 2, 64);
      float xl = pre_l[tau*DK + jrow] + accL;
      float xg = pre_g[tau*DK + jrow] + accG;
      float LG = sigm(xg) * (tanhf(xl) + 1.f) * 0.5f;
      if (p == 0) LG_l[jrow] = LG;
      float sg = 0.f;
      if (tau > 0 && p == 0) sg = sigm(pre_p[tau*DK + jrow] + accY);
      #pragma unroll
      for (int m = 4; m < 64; m <<= 1) sg += __shfl_xor(sg, m, 64);
      if (l == 0) ysum_l[w] = sg;
      if (tau < S_-1) qbuf[(tau+1)&1][tid] = q_matrix[(size_t)ex_id[b*S_+tau+1]*NSK + tid];
    }
    __syncthreads(); // b1
    if (tid == 0 && tau > 0) {
      float s = 0.f;
      #pragma unroll
      for (int i = 0; i < 8; ++i) s += ysum_l[i];
      pred[b*S_ + tau] = s * (1.f/128.f);
    }

    if (tau < S_-1) {
      // ============ G2: cf = pre_f + W_f2 @ LG ; W': refresh h_sh ============
      {
        float accF = 0.f;
        const float* wf2 = W_f + jrow*384 + 128;
        #pragma unroll
        for (int c0 = 0; c0 < 32; c0 += 4) {
          int c = p*32 + c0;
          f32x4 a   = *(const f32x4*)(wf2 + c);
          f32x4 lgv = *(const f32x4*)&LG_l[c];
          accF += a[0]*lgv[0] + a[1]*lgv[1] + a[2]*lgv[2] + a[3]*lgv[3];
        }
        accF += __shfl_xor(accF, 1, 64); accF += __shfl_xor(accF, 2, 64);
        if (p == 0) cf_l[jrow] = pre_f[tau*DK + jrow] + accF;
      }
      // refresh bf16 shadow of h (current master) for this wave's (skill, d-half) cells
      for (int nt = 0; nt < 8; ++nt) {
        int srow = (wn*8 + nt)*16 + lr;
        #pragma unroll
        for (int jt = 0; jt < 4; ++jt) {
          int dbase = wj*64 + jt*16 + lg4*4;
          f32x4 hv = *(const f32x4*)(hm + (size_t)srow*DK + dbase);
          unsigned long long pkv =
              (unsigned long long)f2bf(hv[0])
            | ((unsigned long long)f2bf(hv[1]) << 16)
            | ((unsigned long long)f2bf(hv[2]) << 32)
            | ((unsigned long long)f2bf(hv[3]) << 48);
          int cb = dbase*2;
          *(unsigned long long*)((char*)h_sh + (srow*256 + (cb ^ ((srow&7)<<4)))) = pkv;
        }
      }
      __syncthreads(); // b2

      // ============ M: GEMM + update + h_tilde partials ============
      f32x4 LGr[4], cfr[4];
      #pragma unroll
      for (int jt = 0; jt < 4; ++jt) {
        int dbase = wj*64 + jt*16 + lg4*4;
        LGr[jt] = *(const f32x4*)&LG_l[dbase];
        cfr[jt] = *(const f32x4*)&cf_l[dbase];
      }
      float htp[4][4];
      #pragma unroll
      for (int jt = 0; jt < 4; ++jt)
        #pragma unroll
        for (int r = 0; r < 4; ++r) htp[jt][r] = 0.f;

      const float* qc = qbuf[tau&1];
      const float* qn = qbuf[(tau+1)&1];

      for (int nt = 0; nt < 8; ++nt) {
        int srow = (wn*8 + nt)*16 + lr;
        s16x8 bfr[4];
        #pragma unroll
        for (int k = 0; k < 4; ++k) {
          int cb = (k*32 + lg4*8)*2;
          bfr[k] = *(const s16x8*)((const char*)h_sh + (srow*256 + (cb ^ ((srow&7)<<4))));
        }
        f32x4 acc[4];
        #pragma unroll
        for (int jt = 0; jt < 4; ++jt) acc[jt] = (f32x4){0.f,0.f,0.f,0.f};
        #pragma unroll
        for (int k = 0; k < 4; ++k) {
          #pragma unroll
          for (int jt = 0; jt < 4; ++jt)
            acc[jt] = __builtin_amdgcn_mfma_f32_16x16x32_bf16(as_bf(wfr[jt][k]), as_bf(bfr[k]), acc[jt], 0, 0, 0);
        }
        float qt = qc[srow], qv = qn[srow];
        #pragma unroll
        for (int jt = 0; jt < 4; ++jt) {
          int dbase = wj*64 + jt*16 + lg4*4;
          float* hp = hm + (size_t)srow*DK + dbase;
          f32x4 hv = *(const f32x4*)hp;
          f32x4 hn;
          #pragma unroll
          for (int r = 0; r < 4; ++r) {
            float g = sigm(acc[jt][r] + cfr[jt][r]);
            float x = qt*LGr[jt][r] + g*hv[r];
            hn[r] = x;
            htp[jt][r] += qv*x;
          }
          *(f32x4*)hp = hn;
        }
      }
      // reduce h_tilde partials over the 16 skill-lanes
      #pragma unroll
      for (int jt = 0; jt < 4; ++jt) {
        #pragma unroll
        for (int r = 0; r < 4; ++r) {
          float v = htp[jt][r];
          v += __shfl_xor(v, 1, 64);
          v += __shfl_xor(v, 2, 64);
          v += __shfl_xor(v, 4, 64);
          v += __shfl_xor(v, 8, 64);
          htp[jt][r] = v;
        }
      }
      if (lr == 0) {
        #pragma unroll
        for (int jt = 0; jt < 4; ++jt) {
          int dbase = wj*64 + jt*16 + lg4*4;
          #pragma unroll
          for (int r = 0; r < 4; ++r) htp_l[wn][dbase + r] = htp[jt][r];
        }
      }
      __syncthreads(); // b3
    }
  }
}

extern "C" void kernel_launch(void* const* d_in, const int* in_sizes, int n_in,
                              void* d_out, int out_size, void* d_ws, size_t ws_size,
                              hipStream_t stream) {
  const float* answer   = (const float*)d_in[0];
  const float* q_matrix = (const float*)d_in[1];
  const float* h0       = (const float*)d_in[2];
  const float* E_emb    = (const float*)d_in[3];
  const float* AT_emb   = (const float*)d_in[4];
  const float* IT_emb   = (const float*)d_in[5];
  const float* W_le     = (const float*)d_in[6];
  const float* b_le     = (const float*)d_in[7];
  const float* W_l      = (const float*)d_in[8];
  const float* b_l      = (const float*)d_in[9];
  const float* W_g      = (const float*)d_in[10];
  const float* b_g      = (const float*)d_in[11];
  const float* W_f      = (const float*)d_in[12];
  const float* b_f      = (const float*)d_in[13];
  const float* W_p      = (const float*)d_in[14];
  const float* b_p      = (const float*)d_in[15];
  const int* ex_id      = (const int*)d_in[16];
  const int* at_id      = (const int*)d_in[19];
  const int* it_sec     = (const int*)d_in[20];

  float* ws = (float*)d_ws;
  float* pred = (float*)d_out;

  k_learning<<<dim3(256), dim3(512), 0, stream>>>(E_emb, AT_emb, W_le, b_le, answer,
                                                  ex_id, at_id, ws + LEARN_OFF);
  k_pre<<<dim3(256), dim3(512), 0, stream>>>(IT_emb, E_emb, W_l, b_l, W_g, b_g,
                                             W_f, b_f, W_p, b_p, ex_id, it_sec,
                                             ws + LEARN_OFF, ws);
  k_scan<<<dim3(64), dim3(512), 0, stream>>>(q_matrix, h0, W_l, W_g, W_f, W_p,
                                             ex_id, ws, ws + HM_OFF, pred);
}

// Round 3
// 1845.591 us; speedup vs baseline: 1.0122x; 1.0122x over previous
//
#include <hip/hip_runtime.h>
#include <hip/hip_bf16.h>
#include <stdint.h>

#define B_ 64
#define S_ 50
#define NSK 512
#define DK 128

// ws layout (float offsets)
#define LEARN_OFF 0u
#define PREL_OFF  409600u
#define PREG_OFF  819200u
#define PREF_OFF  1228800u
#define PREP_OFF  1638400u

typedef float  f32x4  __attribute__((ext_vector_type(4)));
typedef short  s16x8  __attribute__((ext_vector_type(8)));
typedef __bf16 bf16x8 __attribute__((ext_vector_type(8)));

static __device__ __forceinline__ bf16x8 as_bf(s16x8 v){ return __builtin_bit_cast(bf16x8, v); }

static __device__ __forceinline__ unsigned short f2bf(float x){
  unsigned int u = __builtin_bit_cast(unsigned int, x);
  u += 0x7FFFu + ((u>>16)&1u);
  return (unsigned short)(u>>16);
}
static __device__ __forceinline__ float sigm(float x){ return 1.f/(1.f + __expf(-x)); }

// -------------------- K1: learning[b,t,j] --------------------
__global__ __launch_bounds__(512) void k_learning(
    const float* __restrict__ E_emb, const float* __restrict__ AT_emb,
    const float* __restrict__ W_le, const float* __restrict__ b_le,
    const float* __restrict__ answer, const int* __restrict__ ex_id,
    const int* __restrict__ at_id, float* __restrict__ learn_ws)
{
  int b = blockIdx.x >> 2, jg = blockIdx.x & 3;
  int tid = threadIdx.x; int w = tid >> 6; int l = tid & 63;
  __shared__ float exv[S_][128];
  __shared__ float atv[S_][128];
  __shared__ float ansv[S_];
  for (int idx = tid; idx < S_*128; idx += 512) {
    int t = idx >> 7, d = idx & 127;
    exv[t][d] = E_emb[(size_t)ex_id[b*S_+t]*128 + d];
    atv[t][d] = AT_emb[(size_t)at_id[b*S_+t]*128 + d];
  }
  if (tid < S_) ansv[tid] = answer[b*S_+tid];
  __syncthreads();
  for (int jj = 0; jj < 4; ++jj) {
    int jrow = jg*32 + w + 8*jj;
    float wv[5];
    int base = l*5;
    #pragma unroll
    for (int q = 0; q < 5; ++q) { int i = base+q; wv[q] = (i < 306) ? W_le[jrow*306 + i] : 0.f; }
    float bj = b_le[jrow];
    for (int t = 0; t < S_; ++t) {
      float pacc = 0.f;
      #pragma unroll
      for (int q = 0; q < 5; ++q) {
        int i = base+q;
        float v = 0.f;
        if (i < 128) v = exv[t][i];
        else if (i < 256) v = atv[t][i-128];
        else if (i < 306) v = ansv[t];
        pacc += wv[q]*v;
      }
      #pragma unroll
      for (int m = 1; m < 64; m <<= 1) pacc += __shfl_xor(pacc, m, 64);
      if (l == 0) learn_ws[(size_t)(b*S_+t)*DK + jrow] = pacc + bj;
    }
  }
}

// -------------------- K2: pre_l/pre_g/pre_f/pre_p --------------------
__global__ __launch_bounds__(512) void k_pre(
    const float* __restrict__ IT_emb, const float* __restrict__ E_emb,
    const float* __restrict__ W_l, const float* __restrict__ b_l,
    const float* __restrict__ W_g, const float* __restrict__ b_g,
    const float* __restrict__ W_f, const float* __restrict__ b_f,
    const float* __restrict__ W_p, const float* __restrict__ b_p,
    const int* __restrict__ ex_id, const int* __restrict__ it_sec,
    const float* __restrict__ learn_ws, float* __restrict__ ws)
{
  int b = blockIdx.x >> 2, jg = blockIdx.x & 3;
  int tid = threadIdx.x; int w = tid >> 6; int l = tid & 63;
  __shared__ float itv[S_][128];
  __shared__ float llds[S_][128];
  __shared__ float exv[S_][128];
  for (int idx = tid; idx < S_*128; idx += 512) {
    int t = idx >> 7, d = idx & 127;
    int itm = it_sec[b*S_+t] / 60; if (itm > 1439) itm = 1439; if (itm < 0) itm = 0;
    itv[t][d]  = IT_emb[(size_t)itm*128 + d];
    llds[t][d] = learn_ws[(size_t)(b*S_+t)*DK + d];
    exv[t][d]  = E_emb[(size_t)ex_id[b*S_+t]*128 + d];
  }
  __syncthreads();
  for (int jj = 0; jj < 4; ++jj) {
    int jrow = jg*32 + w + 8*jj;
    float wl[6], wg[6];
    int base6 = l*6;
    #pragma unroll
    for (int q = 0; q < 6; ++q) { wl[q] = W_l[jrow*512 + base6+q]; wg[q] = W_g[jrow*512 + base6+q]; }
    float wfv[2], wpv[2];
    int base2 = l*2;
    #pragma unroll
    for (int q = 0; q < 2; ++q) { wfv[q] = W_f[jrow*384 + 256 + base2+q]; wpv[q] = W_p[jrow*256 + base2+q]; }
    float bl = b_l[jrow], bg = b_g[jrow], bfs = b_f[jrow], bp = b_p[jrow];
    for (int t = 0; t < S_; ++t) {
      float pl = 0.f, pg = 0.f, pf = 0.f, pp = 0.f;
      #pragma unroll
      for (int q = 0; q < 6; ++q) {
        int i = base6+q;
        float v;
        if (i < 128) v = (t > 0) ? llds[t-1][i] : 0.f;
        else if (i < 256) v = itv[t][i-128];
        else v = llds[t][i-256];
        pl += wl[q]*v; pg += wg[q]*v;
      }
      #pragma unroll
      for (int q = 0; q < 2; ++q) {
        pf += wfv[q]*itv[t][base2+q];
        pp += wpv[q]*exv[t][base2+q];
      }
      #pragma unroll
      for (int m = 1; m < 64; m <<= 1) {
        pl += __shfl_xor(pl, m, 64);
        pg += __shfl_xor(pg, m, 64);
        pf += __shfl_xor(pf, m, 64);
        pp += __shfl_xor(pp, m, 64);
      }
      if (l == 0) {
        size_t o = (size_t)(b*S_+t)*DK + jrow;
        ws[PREL_OFF + o] = pl + bl;
        ws[PREG_OFF + o] = pg + bg;
        ws[PREF_OFF + o] = pf + bfs;
        ws[PREP_OFF + o] = pp + bp;
      }
    }
  }
}

// -------------------- K3: sequential scan (h in VGPRs, fully unrolled) --------------------
__global__ __launch_bounds__(512) void k_scan(
    const float* __restrict__ q_matrix, const float* __restrict__ h0,
    const float* __restrict__ W_l, const float* __restrict__ W_g,
    const float* __restrict__ W_f, const float* __restrict__ W_p,
    const int* __restrict__ ex_id, const float* __restrict__ ws,
    float* __restrict__ pred)
{
  int b = blockIdx.x;
  int tid = threadIdx.x;
  int w  = tid >> 6;          // wave 0..7
  int l  = tid & 63;          // lane
  int wj = w & 1;             // j-half (output-dim half)
  int wn = w >> 1;            // skill quarter
  int lr  = l & 15;
  int lg4 = l >> 4;
  int swz = (lr & 7) << 4;    // row-XOR swizzle (srow&7 == lr&7)

  __shared__ __align__(16) unsigned short h_sh[NSK*DK];  // 128KB bf16, swizzled
  __shared__ float qbuf[2][NSK];
  __shared__ float LG_l[DK];
  __shared__ float cf_l[DK];
  __shared__ float htp_l[4][DK];
  __shared__ float ysum_l[8];

  // ---- W_f1 fragments (A operand), resident in VGPRs ----
  s16x8 wfr[4][4];
  #pragma unroll
  for (int jt = 0; jt < 4; ++jt) {
    #pragma unroll
    for (int k = 0; k < 4; ++k) {
      int jrow_ = wj*64 + jt*16 + lr;
      int dbase = k*32 + lg4*8;
      const float* src = W_f + jrow_*384 + dbase;
      s16x8 f;
      #pragma unroll
      for (int q = 0; q < 8; ++q) f[q] = (short)f2bf(src[q]);
      wfr[jt][k] = f;
    }
  }

  // ---- h master in registers: thread owns 8 rows x 16 dims (static idx only) ----
  f32x4 hreg[8][4];
  #pragma unroll
  for (int nt = 0; nt < 8; ++nt) {
    int srow = (wn*8 + nt)*16 + lr;
    #pragma unroll
    for (int jt = 0; jt < 4; ++jt) {
      int dbase = wj*64 + jt*16 + lg4*4;
      hreg[nt][jt] = *(const f32x4*)(h0 + (size_t)srow*DK + dbase);
    }
  }

  qbuf[0][tid] = q_matrix[(size_t)ex_id[b*S_]*NSK + tid];
  if (tid == 0) pred[b*S_] = 0.f;
  __syncthreads();
  // ---- h_tilde0 partials ----
  {
    int d = tid & 127, g = tid >> 7;
    float acc = 0.f;
    for (int n = g*128; n < g*128 + 128; ++n) acc += qbuf[0][n] * h0[(size_t)n*DK + d];
    htp_l[g][d] = acc;
  }
  __syncthreads();

  const float* pre_l = ws + PREL_OFF + (size_t)b*S_*DK;
  const float* pre_g = ws + PREG_OFF + (size_t)b*S_*DK;
  const float* pre_f = ws + PREF_OFF + (size_t)b*S_*DK;
  const float* pre_p = ws + PREP_OFF + (size_t)b*S_*DK;

  int jrow = tid >> 2, p = tid & 3;

  for (int tau = 0; tau < S_; ++tau) {
    // ================= G1: LG + y(tau) + q staging =================
    {
      float accL = 0.f, accG = 0.f, accY = 0.f;
      const float* wl4 = W_l + jrow*512 + 384;
      const float* wg4 = W_g + jrow*512 + 384;
      const float* wp2 = W_p + jrow*256 + 128;
      #pragma unroll
      for (int c0 = 0; c0 < 32; c0 += 4) {
        int c = p*32 + c0;
        f32x4 t0 = *(const f32x4*)&htp_l[0][c];
        f32x4 t1 = *(const f32x4*)&htp_l[1][c];
        f32x4 t2 = *(const f32x4*)&htp_l[2][c];
        f32x4 t3 = *(const f32x4*)&htp_l[3][c];
        f32x4 hv = t0 + t1 + t2 + t3;
        f32x4 a  = *(const f32x4*)(wl4 + c);
        f32x4 g4 = *(const f32x4*)(wg4 + c);
        f32x4 y4 = *(const f32x4*)(wp2 + c);
        accL += a[0]*hv[0] + a[1]*hv[1] + a[2]*hv[2] + a[3]*hv[3];
        accG += g4[0]*hv[0] + g4[1]*hv[1] + g4[2]*hv[2] + g4[3]*hv[3];
        accY += y4[0]*hv[0] + y4[1]*hv[1] + y4[2]*hv[2] + y4[3]*hv[3];
      }
      accL += __shfl_xor(accL, 1, 64); accL += __shfl_xor(accL, 2, 64);
      accG += __shfl_xor(accG, 1, 64); accG += __shfl_xor(accG, 2, 64);
      accY += __shfl_xor(accY, 1, 64); accY += __shfl_xor(accY, 2, 64);
      float xl = pre_l[tau*DK + jrow] + accL;
      float xg = pre_g[tau*DK + jrow] + accG;
      float LG = sigm(xg) * (tanhf(xl) + 1.f) * 0.5f;
      if (p == 0) LG_l[jrow] = LG;
      float sg = 0.f;
      if (tau > 0 && p == 0) sg = sigm(pre_p[tau*DK + jrow] + accY);
      #pragma unroll
      for (int m = 4; m < 64; m <<= 1) sg += __shfl_xor(sg, m, 64);
      if (l == 0) ysum_l[w] = sg;
      if (tau < S_-1) qbuf[(tau+1)&1][tid] = q_matrix[(size_t)ex_id[b*S_+tau+1]*NSK + tid];
    }
    __syncthreads(); // b1
    if (tid == 0 && tau > 0) {
      float s = 0.f;
      #pragma unroll
      for (int i = 0; i < 8; ++i) s += ysum_l[i];
      pred[b*S_ + tau] = s * (1.f/128.f);
    }

    if (tau < S_-1) {
      // ============ G2: cf = pre_f + W_f2 @ LG ; pack h_sh from hreg ============
      {
        float accF = 0.f;
        const float* wf2 = W_f + jrow*384 + 128;
        #pragma unroll
        for (int c0 = 0; c0 < 32; c0 += 4) {
          int c = p*32 + c0;
          f32x4 a   = *(const f32x4*)(wf2 + c);
          f32x4 lgv = *(const f32x4*)&LG_l[c];
          accF += a[0]*lgv[0] + a[1]*lgv[1] + a[2]*lgv[2] + a[3]*lgv[3];
        }
        accF += __shfl_xor(accF, 1, 64); accF += __shfl_xor(accF, 2, 64);
        if (p == 0) cf_l[jrow] = pre_f[tau*DK + jrow] + accF;
      }
      // pack bf16 shadow of h from registers (static indices, no asm)
      #pragma unroll
      for (int nt = 0; nt < 8; ++nt) {
        int srow = (wn*8 + nt)*16 + lr;
        #pragma unroll
        for (int jt = 0; jt < 4; ++jt) {
          int cb = (wj*64 + jt*16 + lg4*4)*2;
          f32x4 hv = hreg[nt][jt];
          unsigned long long pkv =
              (unsigned long long)f2bf(hv[0])
            | ((unsigned long long)f2bf(hv[1]) << 16)
            | ((unsigned long long)f2bf(hv[2]) << 32)
            | ((unsigned long long)f2bf(hv[3]) << 48);
          *(unsigned long long*)((char*)h_sh + (srow*256 + (cb ^ swz))) = pkv;
        }
      }
      __syncthreads(); // b2

      // ============ M: GEMM (acc init = cf) + update; then h_tilde pass ============
      f32x4 LGr[4], cfr[4];
      #pragma unroll
      for (int jt = 0; jt < 4; ++jt) {
        int dbase = wj*64 + jt*16 + lg4*4;
        LGr[jt] = *(const f32x4*)&LG_l[dbase];
        cfr[jt] = *(const f32x4*)&cf_l[dbase];
      }
      const float* qc = qbuf[tau&1];
      const float* qn = qbuf[(tau+1)&1];

      #pragma unroll
      for (int nt = 0; nt < 8; ++nt) {
        int srow = (wn*8 + nt)*16 + lr;
        const char* rowp = (const char*)h_sh + srow*256;
        f32x4 acc0 = cfr[0], acc1 = cfr[1], acc2 = cfr[2], acc3 = cfr[3];
        #pragma unroll
        for (int k = 0; k < 4; ++k) {
          s16x8 bfr = *(const s16x8*)(rowp + ((k*64 + lg4*16) ^ swz));
          acc0 = __builtin_amdgcn_mfma_f32_16x16x32_bf16(as_bf(wfr[0][k]), as_bf(bfr), acc0, 0, 0, 0);
          acc1 = __builtin_amdgcn_mfma_f32_16x16x32_bf16(as_bf(wfr[1][k]), as_bf(bfr), acc1, 0, 0, 0);
          acc2 = __builtin_amdgcn_mfma_f32_16x16x32_bf16(as_bf(wfr[2][k]), as_bf(bfr), acc2, 0, 0, 0);
          acc3 = __builtin_amdgcn_mfma_f32_16x16x32_bf16(as_bf(wfr[3][k]), as_bf(bfr), acc3, 0, 0, 0);
        }
        float qt = qc[srow];
        #pragma unroll
        for (int r = 0; r < 4; ++r) {
          hreg[nt][0][r] = qt*LGr[0][r] + sigm(acc0[r])*hreg[nt][0][r];
          hreg[nt][1][r] = qt*LGr[1][r] + sigm(acc1[r])*hreg[nt][1][r];
          hreg[nt][2][r] = qt*LGr[2][r] + sigm(acc2[r])*hreg[nt][2][r];
          hreg[nt][3][r] = qt*LGr[3][r] + sigm(acc3[r])*hreg[nt][3][r];
        }
      }

      // h_tilde partial pass (separate so htp doesn't overlap acc liveness)
      f32x4 htp[4];
      #pragma unroll
      for (int jt = 0; jt < 4; ++jt) htp[jt] = (f32x4){0.f,0.f,0.f,0.f};
      #pragma unroll
      for (int nt = 0; nt < 8; ++nt) {
        float qv = qn[(wn*8 + nt)*16 + lr];
        #pragma unroll
        for (int jt = 0; jt < 4; ++jt) htp[jt] += qv * hreg[nt][jt];
      }
      #pragma unroll
      for (int jt = 0; jt < 4; ++jt) {
        #pragma unroll
        for (int r = 0; r < 4; ++r) {
          float v = htp[jt][r];
          v += __shfl_xor(v, 1, 64);
          v += __shfl_xor(v, 2, 64);
          v += __shfl_xor(v, 4, 64);
          v += __shfl_xor(v, 8, 64);
          htp[jt][r] = v;
        }
      }
      if (lr == 0) {
        #pragma unroll
        for (int jt = 0; jt < 4; ++jt) {
          int dbase = wj*64 + jt*16 + lg4*4;
          #pragma unroll
          for (int r = 0; r < 4; ++r) htp_l[wn][dbase + r] = htp[jt][r];
        }
      }
      __syncthreads(); // b3
    }
  }
}

extern "C" void kernel_launch(void* const* d_in, const int* in_sizes, int n_in,
                              void* d_out, int out_size, void* d_ws, size_t ws_size,
                              hipStream_t stream) {
  const float* answer   = (const float*)d_in[0];
  const float* q_matrix = (const float*)d_in[1];
  const float* h0       = (const float*)d_in[2];
  const float* E_emb    = (const float*)d_in[3];
  const float* AT_emb   = (const float*)d_in[4];
  const float* IT_emb   = (const float*)d_in[5];
  const float* W_le     = (const float*)d_in[6];
  const float* b_le     = (const float*)d_in[7];
  const float* W_l      = (const float*)d_in[8];
  const float* b_l      = (const float*)d_in[9];
  const float* W_g      = (const float*)d_in[10];
  const float* b_g      = (const float*)d_in[11];
  const float* W_f      = (const float*)d_in[12];
  const float* b_f      = (const float*)d_in[13];
  const float* W_p      = (const float*)d_in[14];
  const float* b_p      = (const float*)d_in[15];
  const int* ex_id      = (const int*)d_in[16];
  const int* at_id      = (const int*)d_in[19];
  const int* it_sec     = (const int*)d_in[20];

  float* ws = (float*)d_ws;
  float* pred = (float*)d_out;

  k_learning<<<dim3(256), dim3(512), 0, stream>>>(E_emb, AT_emb, W_le, b_le, answer,
                                                  ex_id, at_id, ws + LEARN_OFF);
  k_pre<<<dim3(256), dim3(512), 0, stream>>>(IT_emb, E_emb, W_l, b_l, W_g, b_g,
                                             W_f, b_f, W_p, b_p, ex_id, it_sec,
                                             ws + LEARN_OFF, ws);
  k_scan<<<dim3(64), dim3(512), 0, stream>>>(q_matrix, h0, W_l, W_g, W_f, W_p,
                                             ex_id, ws, pred);
}